// Round 3
// baseline (306.278 us; speedup 1.0000x reference)
//
#include <hip/hip_runtime.h>

// Problem constants (match reference):
//   B=4, GX=480, GY=360, C_IN=64, C_OUT=32, N=480000
#define GXGY  172800        // GX*GY
#define NSEG  691200        // B*GX*GY (multiple of 64; 64-voxel blocks never straddle b)
#define CIN   64
#define COUT  32
#define VPB   64            // voxels per block
#define PSTR  (CIN + 1)     // pooled row stride in LDS (65: bank-conflict-free both phases)

// ---------------------------------------------------------------------------
// Pass A: per-voxel linked lists. head[seg]=-1 init; next[i] = old head.
// ---------------------------------------------------------------------------
__global__ __launch_bounds__(256) void build_lists_kernel(
    const int* __restrict__ ind,   // [N, 2]
    const int* __restrict__ bidx,  // [N]
    int*       __restrict__ head,  // [NSEG]
    int*       __restrict__ next,  // [N]
    int N)
{
    int i = blockIdx.x * 256 + threadIdx.x;
    if (i >= N) return;
    int2 xy = ((const int2*)ind)[i];
    int seg = bidx[i] * GXGY + xy.x * 360 + xy.y;
    next[i] = atomicExch(&head[seg], i);
}

// ---------------------------------------------------------------------------
// Pass B (fused pool+compress). Block = 256 threads = 64 consecutive voxels.
//
// Phase 1: wave w walks chains of voxels w*16..w*16+15 SEQUENTIALLY.
//   - chain control (head/next) is wave-uniform -> zero divergence; empty
//     voxels cost nothing for the whole wave
//   - fea row load = fea[i*64+lane]: one fully-coalesced 256B transaction
//   - next[i]: same-address broadcast load (1 cacheline)
//   - pooled row -> LDS stride 65 (write: consecutive words, conflict-free)
//
// Phase 2: thread (lv = tid&63, g = tid>>6) computes channels g*8..g*8+7 of
//   voxel lv. sP read: addr lv*65+k -> bank (lv+k)%32, 2 lanes/bank = free.
//   sW read: wave-uniform -> broadcast. Stores y-coalesced per channel.
// ---------------------------------------------------------------------------
__global__ __launch_bounds__(256) void pool_compress_kernel(
    const float* __restrict__ fea,   // [N, 64]
    const int*   __restrict__ head,  // [NSEG]
    const int*   __restrict__ next,  // [N]
    const float* __restrict__ W,     // [64, 32] row-major
    const float* __restrict__ bias,  // [32]
    float*       __restrict__ out)   // [B, 32, GX, GY]
{
    __shared__ float sW[CIN * COUT];     // 8 KB
    __shared__ float sb[COUT];
    __shared__ float sP[VPB * PSTR];     // 16.25 KB pooled rows
    __shared__ int   sOcc[VPB];

    int tid  = threadIdx.x;
    int wid  = tid >> 6;
    int lane = tid & 63;

    for (int j = tid; j < CIN * COUT; j += 256) sW[j] = W[j];
    if (tid < COUT) sb[tid] = bias[tid];

    int vbase = blockIdx.x * VPB;

    // Preload this wave's 16 head pointers in one coalesced load.
    int myhead = (lane < 16) ? head[vbase + wid * 16 + lane] : -1;

    // ---- Phase 1: pool 16 voxels per wave ----
    for (int j = 0; j < 16; ++j) {
        int lv = wid * 16 + j;
        int i = __shfl(myhead, j);          // wave-uniform
        if (i < 0) {
            if (lane == 0) sOcc[lv] = 0;
            continue;                        // whole wave skips
        }
        if (lane == 0) sOcc[lv] = 1;
        float m = fea[(size_t)i * CIN + lane];   // coalesced 256B row
        i = next[i];                              // broadcast load
        while (i >= 0) {
            m = fmaxf(m, fea[(size_t)i * CIN + lane]);
            i = next[i];
        }
        sP[lv * PSTR + lane] = m;
    }
    __syncthreads();

    // ---- Phase 2: 64x8 matvec per thread ----
    int lv = lane;          // voxel within block
    int g  = wid;           // channel group: channels g*8 .. g*8+7
    int v  = vbase + lv;
    int b  = v / GXGY;      // block never straddles b (GXGY % 64 == 0)
    int rem = v - b * GXGY;

    float res[8];
    if (sOcc[lv]) {
        float acc[8];
        #pragma unroll
        for (int c = 0; c < 8; ++c) acc[c] = sb[g * 8 + c];
        #pragma unroll
        for (int k = 0; k < CIN; ++k) {
            float p = sP[lv * PSTR + k];
            const float* w = &sW[k * COUT + g * 8];
            #pragma unroll
            for (int c = 0; c < 8; ++c) acc[c] = fmaf(p, w[c], acc[c]);
        }
        #pragma unroll
        for (int c = 0; c < 8; ++c) res[c] = fmaxf(acc[c], 0.0f);
    } else {
        #pragma unroll
        for (int c = 0; c < 8; ++c) res[c] = 0.0f;
    }

    float* op = out + (size_t)b * COUT * GXGY + (size_t)g * 8 * GXGY + rem;
    #pragma unroll
    for (int c = 0; c < 8; ++c) op[c * GXGY] = res[c];
}

extern "C" void kernel_launch(void* const* d_in, const int* in_sizes, int n_in,
                              void* d_out, int out_size, void* d_ws, size_t ws_size,
                              hipStream_t stream)
{
    const float* fea  = (const float*)d_in[0];
    const int*   ind  = (const int*)d_in[1];
    const int*   bidx = (const int*)d_in[2];
    const float* W    = (const float*)d_in[3];
    const float* bias = (const float*)d_in[4];
    float*       out  = (float*)d_out;

    int N = in_sizes[0] / CIN;  // 480000

    int* head = (int*)d_ws;           // NSEG ints (2.76 MB)
    int* next = (int*)d_ws + NSEG;    // N ints (1.92 MB)

    hipMemsetAsync(head, 0xFF, (size_t)NSEG * sizeof(int), stream);
    build_lists_kernel<<<(N + 255) / 256, 256, 0, stream>>>(ind, bidx, head, next, N);
    pool_compress_kernel<<<NSEG / VPB, 256, 0, stream>>>(fea, head, next, W, bias, out);
}

// Round 4
// 258.687 us; speedup vs baseline: 1.1840x; 1.1840x over previous
//
#include <hip/hip_runtime.h>

// Problem constants: B=4, GX=480, GY=360, C_IN=64, C_OUT=32, N=480000
#define GXGY  172800        // GX*GY (multiple of 64: blocks never straddle batch)
#define NSEG  691200        // B*GX*GY
#define CIN   64
#define COUT  32
#define VPB   64            // voxels per block
#define PSTR  65            // pooled LDS stride: phase-2 bank = (lv+k)%32 -> 2-way = free

// ---------------------------------------------------------------------------
// Pass A: per-voxel linked lists. head[seg]=-1 init; next[i] = old head.
// ---------------------------------------------------------------------------
__global__ __launch_bounds__(256) void build_lists_kernel(
    const int* __restrict__ ind,   // [N, 2]
    const int* __restrict__ bidx,  // [N]
    int*       __restrict__ head,  // [NSEG]
    int*       __restrict__ next,  // [N]
    int N)
{
    int i = blockIdx.x * 256 + threadIdx.x;
    if (i >= N) return;
    int2 xy = ((const int2*)ind)[i];
    int seg = bidx[i] * GXGY + xy.x * 360 + xy.y;
    next[i] = atomicExch(&head[seg], i);
}

// ---------------------------------------------------------------------------
// Pass B (fused pool+compress). Block = 256 threads = 64 voxels. NO W in LDS.
//
// Phase 1: each wave = 4 subgroups of 16 lanes; subgroup walks one voxel
//   chain (4 chains in parallel per wave, 4 sequential rounds -> 16 voxels).
//   - fea row: 16 lanes x float4 = 256B fully coalesced per subgroup
//   - next[i]: subgroup-uniform broadcast load
//   - pooled float4 -> sP rows (stride 65), 4x ds_write_b32 per round
//
// Phase 2: thread (lv=tid&63, g=tid>>6) -> channels g*8..g*8+7 of voxel lv.
//   - W/bias via readfirstlane-forced UNIFORM loads -> SMEM (s_load), SGPR
//     operands broadcast into v_fmac for free: zero LDS-pipe traffic for W
//     (this was R2/R3's bottleneck: ~1900 LDS cyc/wave of W broadcasts)
//   - pooled: 64x ds_read_b32, bank (lv+k)%32 -> 2 lanes/bank = conflict-free
//   - stores y-coalesced per channel
// ---------------------------------------------------------------------------
__global__ __launch_bounds__(256) void pool_compress_kernel(
    const float* __restrict__ fea,   // [N, 64]
    const int*   __restrict__ head,  // [NSEG]
    const int*   __restrict__ next,  // [N]
    const float* __restrict__ W,     // [64, 32] row-major
    const float* __restrict__ bias,  // [32]
    float*       __restrict__ out)   // [B, 32, GX, GY]
{
    __shared__ float sP[VPB * PSTR];   // 16.25 KB pooled rows
    __shared__ int   sOcc[VPB];

    int tid  = threadIdx.x;
    int wid  = tid >> 6;
    int lane = tid & 63;
    int sub  = lane >> 4;    // subgroup 0..3
    int sl   = lane & 15;    // lane within subgroup

    int vbase = blockIdx.x * VPB;

    // Preload this wave's 16 head pointers (coalesced).
    int heads = (lane < 16) ? head[vbase + wid * 16 + lane] : -1;

    // ---- Phase 1: 4 chains in parallel, 4 rounds ----
    for (int j = 0; j < 4; ++j) {
        int lv = wid * 16 + j * 4 + sub;
        int i = __shfl(heads, j * 4 + sub);      // subgroup-uniform
        if (sl == 0) sOcc[lv] = (i >= 0) ? 1 : 0;
        if (i >= 0) {
            const float4* fp = (const float4*)(fea + (size_t)i * CIN) + sl;
            float4 m = *fp;                       // 256B coalesced per subgroup
            i = next[i];                          // broadcast load
            while (i >= 0) {
                float4 t = *((const float4*)(fea + (size_t)i * CIN) + sl);
                m.x = fmaxf(m.x, t.x);
                m.y = fmaxf(m.y, t.y);
                m.z = fmaxf(m.z, t.z);
                m.w = fmaxf(m.w, t.w);
                i = next[i];
            }
            float* dst = &sP[lv * PSTR + sl * 4];
            dst[0] = m.x; dst[1] = m.y; dst[2] = m.z; dst[3] = m.w;
        }
    }
    __syncthreads();

    // ---- Phase 2: 64x8 matvec per thread, W from SMEM ----
    int lv = lane;                                   // voxel within block
    int g  = __builtin_amdgcn_readfirstlane(wid);    // force wave-uniform SGPR
    int b  = vbase / GXGY;                           // uniform per block
    int rem = vbase - b * GXGY + lv;

    const float* Wg = W + g * 8;                     // uniform base -> s_load
    const float* bg = bias + g * 8;

    float res[8];
    if (sOcc[lv]) {
        float acc[8];
        #pragma unroll
        for (int c = 0; c < 8; ++c) acc[c] = bg[c];
        #pragma unroll 16
        for (int k = 0; k < CIN; ++k) {
            float p = sP[lv * PSTR + k];             // 2-way bank = free
            #pragma unroll
            for (int c = 0; c < 8; ++c)
                acc[c] = fmaf(p, Wg[k * COUT + c], acc[c]);
        }
        #pragma unroll
        for (int c = 0; c < 8; ++c) res[c] = fmaxf(acc[c], 0.0f);
    } else {
        #pragma unroll
        for (int c = 0; c < 8; ++c) res[c] = 0.0f;
    }

    float* op = out + (size_t)b * COUT * GXGY + (size_t)g * 8 * GXGY + rem;
    #pragma unroll
    for (int c = 0; c < 8; ++c) op[c * GXGY] = res[c];
}

extern "C" void kernel_launch(void* const* d_in, const int* in_sizes, int n_in,
                              void* d_out, int out_size, void* d_ws, size_t ws_size,
                              hipStream_t stream)
{
    const float* fea  = (const float*)d_in[0];
    const int*   ind  = (const int*)d_in[1];
    const int*   bidx = (const int*)d_in[2];
    const float* W    = (const float*)d_in[3];
    const float* bias = (const float*)d_in[4];
    float*       out  = (float*)d_out;

    int N = in_sizes[0] / CIN;  // 480000

    int* head = (int*)d_ws;           // NSEG ints (2.76 MB)
    int* next = (int*)d_ws + NSEG;    // N ints (1.92 MB)

    hipMemsetAsync(head, 0xFF, (size_t)NSEG * sizeof(int), stream);
    build_lists_kernel<<<(N + 255) / 256, 256, 0, stream>>>(ind, bidx, head, next, N);
    pool_compress_kernel<<<NSEG / VPB, 256, 0, stream>>>(fea, head, next, W, bias, out);
}

// Round 5
// 255.954 us; speedup vs baseline: 1.1966x; 1.0107x over previous
//
#include <hip/hip_runtime.h>

// Problem constants: B=4, GX=480, GY=360, C_IN=64, C_OUT=32, N=480000
#define GXGY  172800        // GX*GY (multiple of 64: blocks never straddle batch)
#define NSEG  691200        // B*GX*GY
#define CIN   64
#define COUT  32
#define VPB   64            // voxels per block
#define PSTR  65            // pooled LDS stride: phase-2 bank=(lv+k)%32 -> 2-way = free

// ---------------------------------------------------------------------------
// Pass A: per-voxel linked lists. head[seg]=-1 init; next[i] = old head.
// ---------------------------------------------------------------------------
__global__ __launch_bounds__(256) void build_lists_kernel(
    const int* __restrict__ ind,   // [N, 2]
    const int* __restrict__ bidx,  // [N]
    int*       __restrict__ head,  // [NSEG]
    int*       __restrict__ next,  // [N]
    int N)
{
    int i = blockIdx.x * 256 + threadIdx.x;
    if (i >= N) return;
    int2 xy = ((const int2*)ind)[i];
    int seg = bidx[i] * GXGY + xy.x * 360 + xy.y;
    next[i] = atomicExch(&head[seg], i);
}

// ---------------------------------------------------------------------------
// Pass B (fused pool+compress). Block = 256 threads = 64 voxels.
//
// Phase 1 (R5 change): each 16-lane subgroup walks its 4 chains
//   CONCURRENTLY (reg state: 4x float4 maxima + 4 indices). One while-loop;
//   each iteration issues up to 4 independent fea-row loads + 4 next loads
//   per subgroup -> 4x the memory-level parallelism of R4's sequential
//   rounds; serial depth = max chain over 16 wave-chains, not the sum.
//   - fea row: 16 lanes x float4 = 256B coalesced per subgroup
//   - next[i]: subgroup-uniform broadcast load (L2-resident, 1.9 MB)
//
// Phase 2 (unchanged from R4): thread (lv=tid&63, g=tid>>6) -> channels
//   g*8..g*8+7 of voxel lv. W/bias via readfirstlane-forced uniform loads
//   -> SMEM broadcast (zero LDS-pipe cost). sP read 2-way bank = free.
//   Stores y-coalesced per channel.
// ---------------------------------------------------------------------------
__global__ __launch_bounds__(256) void pool_compress_kernel(
    const float* __restrict__ fea,   // [N, 64]
    const int*   __restrict__ head,  // [NSEG]
    const int*   __restrict__ next,  // [N]
    const float* __restrict__ W,     // [64, 32] row-major
    const float* __restrict__ bias,  // [32]
    float*       __restrict__ out)   // [B, 32, GX, GY]
{
    __shared__ float sP[VPB * PSTR];   // 16.25 KB pooled rows
    __shared__ int   sOcc[VPB];

    int tid  = threadIdx.x;
    int wid  = tid >> 6;
    int lane = tid & 63;
    int sub  = lane >> 4;    // subgroup 0..3
    int sl   = lane & 15;    // lane within subgroup

    int vbase = blockIdx.x * VPB;

    // This wave's 16 head pointers in one coalesced load, then distribute.
    int heads = (lane < 16) ? head[vbase + wid * 16 + lane] : -1;

    int idx[4];
    #pragma unroll
    for (int q = 0; q < 4; ++q) idx[q] = __shfl(heads, q * 4 + sub);

    unsigned occm = 0;
    #pragma unroll
    for (int q = 0; q < 4; ++q) if (idx[q] >= 0) occm |= (1u << q);

    if (sl == 0) {
        #pragma unroll
        for (int q = 0; q < 4; ++q)
            sOcc[wid * 16 + q * 4 + sub] = (occm >> q) & 1u;
    }

    // ---- Phase 1: 16 chains per wave, all concurrent ----
    float4 m[4];
    #pragma unroll
    for (int q = 0; q < 4; ++q) {
        if (idx[q] >= 0) {
            m[q] = *((const float4*)(fea + (size_t)idx[q] * CIN) + sl);
            idx[q] = next[idx[q]];
        }
    }
    while (idx[0] >= 0 || idx[1] >= 0 || idx[2] >= 0 || idx[3] >= 0) {
        #pragma unroll
        for (int q = 0; q < 4; ++q) {
            if (idx[q] >= 0) {
                float4 t = *((const float4*)(fea + (size_t)idx[q] * CIN) + sl);
                m[q].x = fmaxf(m[q].x, t.x);
                m[q].y = fmaxf(m[q].y, t.y);
                m[q].z = fmaxf(m[q].z, t.z);
                m[q].w = fmaxf(m[q].w, t.w);
                idx[q] = next[idx[q]];
            }
        }
    }
    #pragma unroll
    for (int q = 0; q < 4; ++q) {
        if (occm & (1u << q)) {
            int lv = wid * 16 + q * 4 + sub;
            float* dst = &sP[lv * PSTR + sl * 4];
            dst[0] = m[q].x; dst[1] = m[q].y; dst[2] = m[q].z; dst[3] = m[q].w;
        }
    }
    __syncthreads();

    // ---- Phase 2: 64x8 matvec per thread, W from SMEM ----
    int lv = lane;                                   // voxel within block
    int g  = __builtin_amdgcn_readfirstlane(wid);    // wave-uniform SGPR
    int b  = vbase / GXGY;                           // uniform per block
    int rem = vbase - b * GXGY + lv;

    const float* Wg = W + g * 8;                     // uniform base -> s_load
    const float* bg = bias + g * 8;

    float res[8];
    if (sOcc[lv]) {
        float acc[8];
        #pragma unroll
        for (int c = 0; c < 8; ++c) acc[c] = bg[c];
        #pragma unroll 16
        for (int k = 0; k < CIN; ++k) {
            float p = sP[lv * PSTR + k];             // 2-way bank = free
            #pragma unroll
            for (int c = 0; c < 8; ++c)
                acc[c] = fmaf(p, Wg[k * COUT + c], acc[c]);
        }
        #pragma unroll
        for (int c = 0; c < 8; ++c) res[c] = fmaxf(acc[c], 0.0f);
    } else {
        #pragma unroll
        for (int c = 0; c < 8; ++c) res[c] = 0.0f;
    }

    float* op = out + (size_t)b * COUT * GXGY + (size_t)g * 8 * GXGY + rem;
    #pragma unroll
    for (int c = 0; c < 8; ++c) op[c * GXGY] = res[c];
}

extern "C" void kernel_launch(void* const* d_in, const int* in_sizes, int n_in,
                              void* d_out, int out_size, void* d_ws, size_t ws_size,
                              hipStream_t stream)
{
    const float* fea  = (const float*)d_in[0];
    const int*   ind  = (const int*)d_in[1];
    const int*   bidx = (const int*)d_in[2];
    const float* W    = (const float*)d_in[3];
    const float* bias = (const float*)d_in[4];
    float*       out  = (float*)d_out;

    int N = in_sizes[0] / CIN;  // 480000

    int* head = (int*)d_ws;           // NSEG ints (2.76 MB)
    int* next = (int*)d_ws + NSEG;    // N ints (1.92 MB)

    hipMemsetAsync(head, 0xFF, (size_t)NSEG * sizeof(int), stream);
    build_lists_kernel<<<(N + 255) / 256, 256, 0, stream>>>(ind, bidx, head, next, N);
    pool_compress_kernel<<<NSEG / VPB, 256, 0, stream>>>(fea, head, next, W, bias, out);
}